// Round 2
// baseline (226.818 us; speedup 1.0000x reference)
//
#include <hip/hip_runtime.h>
#include <math.h>

#define BB 8
#define CCH 32
#define HH 128
#define WW 128
#define OUTC 32
#define NPTS 16
#define NPIX (BB*HH*WW)          // 131072
#define HWP 131                   // Hp-1 = Wp-1 = 131

// workspace layout in floats
#define WS_XT 0                                  // B*H*W*C = 4194304 floats
#define WS_CONV4 (BB*HH*WW*CCH)                  // 4194304
#define WS_STATS (WS_CONV4 + BB*HH*WW*4)         // 4718592 (8 floats: 4 sums, 4 sumsq)
#define WS_BNAB  (WS_STATS + 8)                  // 8 floats: a[4], b[4]
#define WS_WK2   (WS_BNAB + 8)                   // 16384 floats, layout [n][c][o]

__constant__ float c_prfx[16] = {-2,-2,-2,-2, -2,-1, 0, 1,  2, 2, 2, 2, -1, 0, 1, 2};
__constant__ float c_prfy[16] = {-2,-1, 0, 1,  2, 2, 2, 2, -1, 0, 1, 2, -2,-2,-2,-2};

// ---------------- K1: transpose x (B,C,H,W) -> x_t (B,H,W,C); zero stats ---
__global__ __launch_bounds__(256) void k_transpose(const float* __restrict__ x,
                                                   float* __restrict__ ws) {
    __shared__ float tile[32][33];
    int blk = blockIdx.x;            // b*H*(W/32)
    int j0 = (blk & 3) << 5;
    int bi = blk >> 2;               // b*H + i
    int b = bi >> 7, i = bi & 127;
    int tx = threadIdx.x & 31;
    int ty = threadIdx.x >> 5;       // 0..7
    #pragma unroll
    for (int c = ty; c < 32; c += 8)
        tile[c][tx] = x[(((size_t)b*CCH + c)*HH + i)*WW + j0 + tx];
    __syncthreads();
    float* xt = ws + WS_XT;
    #pragma unroll
    for (int jj = ty; jj < 32; jj += 8)
        xt[(((size_t)bi)*WW + j0 + jj)*CCH + tx] = tile[tx][jj];
    if (blk == 0 && threadIdx.x < 8) ws[WS_STATS + threadIdx.x] = 0.f;
}

// ---------------- K2: the two 7-tap convs + bias, store pre-BN, batch stats --
__global__ __launch_bounds__(256) void k_conv(float* __restrict__ ws,
        const float* __restrict__ w_vrt, const float* __restrict__ b_vrt,
        const float* __restrict__ w_hrz, const float* __restrict__ b_hrz) {
    const float* xt = ws + WS_XT;
    int idx = blockIdx.x * 256 + threadIdx.x;
    int b = idx >> 14, ij = idx & 16383, i = ij >> 7, j = ij & 127;
    const float* xb = xt + (size_t)b * (HH*WW*CCH);
    float v0 = 0.f, v1 = 0.f, h0 = 0.f, h1 = 0.f;
    // vertical conv: kernel (2,C,7,1), zero pad 3 in H
    for (int k = 0; k < 7; k++) {
        int r = i + k - 3;
        if (r < 0 || r >= HH) continue;
        const float4* p = (const float4*)(xb + ((size_t)r*WW + j)*CCH);
        #pragma unroll
        for (int c4 = 0; c4 < 8; c4++) {
            float4 xv = p[c4];
            int cb = c4 * 4;
            v0 += w_vrt[(cb+0)*7+k]*xv.x + w_vrt[(cb+1)*7+k]*xv.y
                + w_vrt[(cb+2)*7+k]*xv.z + w_vrt[(cb+3)*7+k]*xv.w;
            v1 += w_vrt[(32+cb+0)*7+k]*xv.x + w_vrt[(32+cb+1)*7+k]*xv.y
                + w_vrt[(32+cb+2)*7+k]*xv.z + w_vrt[(32+cb+3)*7+k]*xv.w;
        }
    }
    // horizontal conv: kernel (2,C,1,7), zero pad 3 in W
    for (int k = 0; k < 7; k++) {
        int cJ = j + k - 3;
        if (cJ < 0 || cJ >= WW) continue;
        const float4* p = (const float4*)(xb + ((size_t)i*WW + cJ)*CCH);
        #pragma unroll
        for (int c4 = 0; c4 < 8; c4++) {
            float4 xv = p[c4];
            int cb = c4 * 4;
            h0 += w_hrz[(cb+0)*7+k]*xv.x + w_hrz[(cb+1)*7+k]*xv.y
                + w_hrz[(cb+2)*7+k]*xv.z + w_hrz[(cb+3)*7+k]*xv.w;
            h1 += w_hrz[(32+cb+0)*7+k]*xv.x + w_hrz[(32+cb+1)*7+k]*xv.y
                + w_hrz[(32+cb+2)*7+k]*xv.z + w_hrz[(32+cb+3)*7+k]*xv.w;
        }
    }
    v0 += b_vrt[0]; v1 += b_vrt[1]; h0 += b_hrz[0]; h1 += b_hrz[1];
    float4* conv4 = (float4*)(ws + WS_CONV4);
    conv4[idx] = make_float4(v0, v1, h0, h1);
    // block reduction of sum + sumsq for 4 channels
    __shared__ float sred[4][8];
    float q[8] = {v0, v1, h0, h1, v0*v0, v1*v1, h0*h0, h1*h1};
    int lane = threadIdx.x & 63, wave = threadIdx.x >> 6;
    #pragma unroll
    for (int t = 0; t < 8; t++) {
        float s = q[t];
        for (int off = 32; off; off >>= 1) s += __shfl_down(s, off);
        if (lane == 0) sred[wave][t] = s;
    }
    __syncthreads();
    if (threadIdx.x < 8) {
        float s = sred[0][threadIdx.x] + sred[1][threadIdx.x]
                + sred[2][threadIdx.x] + sred[3][threadIdx.x];
        atomicAdd(ws + WS_STATS + threadIdx.x, s);
    }
}

// ---------------- K3: BN affine consts + w_pk reorder to [n][c][o] ----------
__global__ void k_prep(const float* __restrict__ w_pk,
        const float* __restrict__ g_vrt, const float* __restrict__ be_vrt,
        const float* __restrict__ g_hrz, const float* __restrict__ be_hrz,
        float* __restrict__ ws) {
    int t = threadIdx.x;
    float* wk2 = ws + WS_WK2;
    for (int e = t; e < 16384; e += 256) {
        int n = e >> 10, c = (e >> 5) & 31, o = e & 31;
        wk2[e] = w_pk[((o*32 + c) << 4) + n];
    }
    if (t < 4) {
        const float cnt = (float)NPIX;
        float sum = ws[WS_STATS + t], sq = ws[WS_STATS + 4 + t];
        float mean = sum / cnt;
        float var  = sq / cnt - mean * mean;
        float gamma = (t < 2) ? g_vrt[t] : g_hrz[t - 2];
        float beta  = (t < 2) ? be_vrt[t] : be_hrz[t - 2];
        float a = gamma * rsqrtf(var + 1e-5f);
        ws[WS_BNAB + t]     = a;
        ws[WS_BNAB + 4 + t] = beta - mean * a;
    }
}

// ---------------- K4: deformable sample + 32x512 matvec per pixel -----------
__global__ __launch_bounds__(256, 2) void k_main(const float* __restrict__ ws,
        const float* __restrict__ b_pk, float* __restrict__ out) {
    const float* xt    = ws + WS_XT;
    const float* bnab  = ws + WS_BNAB;
    const float* wk2   = ws + WS_WK2;
    int idx = blockIdx.x * 256 + threadIdx.x;
    int b = idx >> 14, ij = idx & 16383, i = ij >> 7, j = ij & 127;

    // center values x[b,:,i,j]
    float xc[32];
    const float4* xp = (const float4*)(xt + (size_t)idx * 32);
    #pragma unroll
    for (int c4 = 0; c4 < 8; c4++) {
        float4 v = xp[c4];
        xc[c4*4+0] = v.x; xc[c4*4+1] = v.y; xc[c4*4+2] = v.z; xc[c4*4+3] = v.w;
    }
    // gate values
    const float4* conv4 = (const float4*)(ws + WS_CONV4);
    float4 cv = conv4[idx];
    float gbv[4];
    gbv[0] = 2.f / (1.f + expf(-(cv.x * bnab[0] + bnab[4])));
    gbv[1] = 2.f / (1.f + expf(-(cv.y * bnab[1] + bnab[5])));
    gbv[2] = 2.f / (1.f + expf(-(cv.z * bnab[2] + bnab[6])));
    gbv[3] = 2.f / (1.f + expf(-(cv.w * bnab[3] + bnab[7])));

    float acc[32];
    #pragma unroll
    for (int o = 0; o < 32; o++) acc[o] = b_pk[o];

    const float* xb = xt + (size_t)b * (HH*WW*CCH);
    float fi = (float)i + 2.f, fj = (float)j + 2.f;

    #pragma unroll 1
    for (int n = 0; n < 16; n++) {
        float mx = 0.f, my = 0.f;
        if (n < 4)       mx = -gbv[0];
        else if (n < 8)  my =  gbv[3];
        else if (n < 12) mx =  gbv[1];
        else             my = -gbv[2];
        float px = fi + c_prfx[n] + mx;
        float py = fj + c_prfy[n] + my;
        float qlx = floorf(px), qly = floorf(py);
        int qlxi = min(max((int)qlx, 0), HWP);
        int qlyi = min(max((int)qly, 0), HWP);
        int qrxi = min(max((int)qlx + 1, 0), HWP);
        int qryi = min(max((int)qly + 1, 0), HWP);
        float pxc = fminf(fmaxf(px, 0.f), (float)HWP);
        float pyc = fminf(fmaxf(py, 0.f), (float)HWP);
        float glt = (1.f + ((float)qlxi - pxc)) * (1.f + ((float)qlyi - pyc));
        float grb = (1.f - ((float)qrxi - pxc)) * (1.f - ((float)qryi - pyc));
        // edge pad: x_pad[a] = x[clamp(a-2,0,127)]
        int ltr = min(max(qlxi - 2, 0), HH - 1), ltc = min(max(qlyi - 2, 0), WW - 1);
        int rbr = min(max(qrxi - 2, 0), HH - 1), rbc = min(max(qryi - 2, 0), WW - 1);
        const float4* plt = (const float4*)(xb + ((size_t)ltr * WW + ltc) * CCH);
        const float4* prb = (const float4*)(xb + ((size_t)rbr * WW + rbc) * CCH);
        const float* wn = wk2 + n * 1024;       // [c][o], o contiguous (wave-uniform)
        #pragma unroll
        for (int c4 = 0; c4 < 8; c4++) {
            float4 a = plt[c4], r = prb[c4];
            float d0 = xc[c4*4+0] - (glt * a.x + grb * r.x);
            float d1 = xc[c4*4+1] - (glt * a.y + grb * r.y);
            float d2 = xc[c4*4+2] - (glt * a.z + grb * r.z);
            float d3 = xc[c4*4+3] - (glt * a.w + grb * r.w);
            const float* w0 = wn + c4 * 128;
            #pragma unroll
            for (int o = 0; o < 32; o++) {
                acc[o] += w0[o] * d0 + w0[32+o] * d1 + w0[64+o] * d2 + w0[96+o] * d3;
            }
        }
    }
    float* op = out + (size_t)b * (OUTC*HH*WW) + ij;
    #pragma unroll
    for (int o = 0; o < 32; o++) op[(size_t)o * (HH*WW)] = acc[o];
}

extern "C" void kernel_launch(void* const* d_in, const int* in_sizes, int n_in,
                              void* d_out, int out_size, void* d_ws, size_t ws_size,
                              hipStream_t stream) {
    const float* x      = (const float*)d_in[0];
    const float* w_vrt  = (const float*)d_in[1];
    const float* b_vrt  = (const float*)d_in[2];
    const float* g_vrt  = (const float*)d_in[3];
    const float* be_vrt = (const float*)d_in[4];
    const float* w_hrz  = (const float*)d_in[5];
    const float* b_hrz  = (const float*)d_in[6];
    const float* g_hrz  = (const float*)d_in[7];
    const float* be_hrz = (const float*)d_in[8];
    const float* w_pk   = (const float*)d_in[9];
    const float* b_pk   = (const float*)d_in[10];
    float* ws  = (float*)d_ws;
    float* out = (float*)d_out;

    k_transpose<<<BB*HH*(WW/32), 256, 0, stream>>>(x, ws);
    k_conv<<<NPIX/256, 256, 0, stream>>>(ws, w_vrt, b_vrt, w_hrz, b_hrz);
    k_prep<<<1, 256, 0, stream>>>(w_pk, g_vrt, be_vrt, g_hrz, be_hrz, ws);
    k_main<<<NPIX/256, 256, 0, stream>>>(ws, b_pk, out);
}